// Round 14
// baseline (109.061 us; speedup 1.0000x reference)
//
#include <hip/hip_runtime.h>
#include <hip/hip_bf16.h>

typedef __attribute__((ext_vector_type(8))) short short8;
typedef __attribute__((ext_vector_type(4))) float f32x4;
typedef __attribute__((ext_vector_type(16))) float f32x16;

#define T_    2048
#define QKVN  1536
#define DOUT_ 1024

__device__ __forceinline__ unsigned short bf16r(float f) {
    union { float f; unsigned u; } v; v.f = f;
    unsigned r = v.u + 0x7fffu + ((v.u >> 16) & 1u);   // round-to-nearest-even
    return (unsigned short)(r >> 16);
}
__device__ __forceinline__ float fbf16(short s) {
    union { unsigned u; float f; } v; v.u = ((unsigned)(unsigned short)s) << 16;
    return v.f;
}
__device__ __forceinline__ void plswap(unsigned &a, unsigned &b) {
    asm volatile("v_permlane32_swap_b32 %0, %1" : "+v"(a), "+v"(b));
}
// packed f32x2 -> bf16x2 (RNE), one HW instruction
__device__ __forceinline__ unsigned cvtpk(float lo, float hi) {
    unsigned r;
    asm("v_cvt_pk_bf16_f32 %0, %1, %2" : "=v"(r) : "v"(lo), "v"(hi));
    return r;
}
// async global->LDS, 16B per lane; LDS dest = wave-uniform base + lane*16
__device__ __forceinline__ void gload_lds16(const void* g, void* l) {
    __builtin_amdgcn_global_load_lds(
        (const __attribute__((address_space(1))) void*)g,
        (__attribute__((address_space(3))) void*)l, 16, 0, 0);
}

// Fused pre-pass: blocks 0-255 Wq^T, 256-319 Wk^T, 320-383 Wv^T, 384-639 Wo^T,
// 640-1663 x->bf16 (2 grid-stride reps).
__global__ __launch_bounds__(256)
void k_prep(const float* __restrict__ x, const float* __restrict__ Wq,
            const float* __restrict__ Wk, const float* __restrict__ Wv,
            const float* __restrict__ Wo, short* __restrict__ XB,
            short* __restrict__ WT, short* __restrict__ WoT) {
    __shared__ short tile[64][72];
    int blk = blockIdx.x;
    int t = threadIdx.x;
    if (blk >= 640) {                        // x f32 -> bf16, 8 elems/thread
        int i = (blk - 640) * 256 + t;
#pragma unroll
        for (int rep = 0; rep < 2; rep++, i += 262144) {
            const float* s = x + (size_t)i * 8;
            float4 f1 = *(const float4*)s;
            float4 f2 = *(const float4*)(s + 4);
            uint4 o;
            o.x = (unsigned)bf16r(f1.x) | ((unsigned)bf16r(f1.y) << 16);
            o.y = (unsigned)bf16r(f1.z) | ((unsigned)bf16r(f1.w) << 16);
            o.z = (unsigned)bf16r(f2.x) | ((unsigned)bf16r(f2.y) << 16);
            o.w = (unsigned)bf16r(f2.z) | ((unsigned)bf16r(f2.w) << 16);
            *(uint4*)(XB + (size_t)i * 8) = o;
        }
        return;
    }
    const float* src; short* dst; int N, bx, by;
    if (blk < 256)      { src = Wq; dst = WT;              N = 1024; bx = blk & 15;         by = blk >> 4; }
    else if (blk < 320) { src = Wk; dst = WT + 1024*1024;  N = 256;  bx = (blk-256) & 15;   by = (blk-256) >> 4; }
    else if (blk < 384) { src = Wv; dst = WT + 1280*1024;  N = 256;  bx = (blk-320) & 15;   by = (blk-320) >> 4; }
    else                { src = Wo; dst = WoT;             N = 1024; bx = (blk-384) & 15;   by = (blk-384) >> 4; }
    const int K = 1024;
    int tk = bx * 64, tn = by * 64;
    int r4 = t >> 6, c = t & 63;
#pragma unroll
    for (int i = 0; i < 16; i++) {
        int row = i * 4 + r4;
        tile[c][row] = (short)bf16r(src[(size_t)(tk + row) * N + tn + c]);
    }
    __syncthreads();
    int row = t >> 2, seg = t & 3;
    short8 a = *(const short8*)&tile[row][seg * 16];
    short8 b = *(const short8*)&tile[row][seg * 16 + 8];
    *(short8*)&dst[(size_t)(tn + row) * K + tk + seg * 16]     = a;
    *(short8*)&dst[(size_t)(tn + row) * K + tk + seg * 16 + 8] = b;
}

// V region of QKV -> VT [b][g][d=64][2048 keys]
__global__ __launch_bounds__(256)
void k_vt(const short* __restrict__ qkv, short* __restrict__ vt) {
    __shared__ short tile[64][72];
    int bid = blockIdx.x;
    int b = bid & 1, g = (bid >> 1) & 3, tt = bid >> 3;
    int t0v = tt * 64;
    int tid = threadIdx.x;
    int row = tid >> 2, sp = tid & 3;
    const short* src = qkv + ((size_t)(b * T_ + t0v + row) * QKVN + 1280 + g * 64 + sp * 16);
    uint4 a = *(const uint4*)src;
    uint4 c2 = *(const uint4*)(src + 8);
    const short* ap = (const short*)&a;
    const short* cp = (const short*)&c2;
#pragma unroll
    for (int x = 0; x < 8; x++) tile[sp * 16 + x][row]     = ap[x];
#pragma unroll
    for (int x = 0; x < 8; x++) tile[sp * 16 + 8 + x][row] = cp[x];
    __syncthreads();
    int d = tid >> 2;
    short* dst = vt + ((size_t)((b * 4 + g) * 64 + d) * T_ + t0v + sp * 16);
    *(uint4*)dst       = *(const uint4*)&tile[d][sp * 16];
    *(uint4*)(dst + 8) = *(const uint4*)&tile[d][sp * 16 + 8];
}

// C[M][N] = A[M][K] * Bt[N][K]^T, bf16. Tile 128x128 (m97-style), BK=64,
// gload_lds w16 staging, both-sides XOR swizzle, 4 waves x (64x64) wave-tile,
// 1D grid with bijective XCD swizzle. M/128 must be 32.
template <int CF32, int ROPE>
__global__ __launch_bounds__(256, 3)
void k_gemm(const short* __restrict__ A, const short* __restrict__ Bt,
            void* __restrict__ Cv, int M, int N, int K,
            const float* __restrict__ cosT, const float* __restrict__ sinT) {
    __shared__ __align__(16) short As[128][64];
    __shared__ __align__(16) short Bs[128][64];
    int nwg = gridDim.x;
    int per = nwg >> 3;                            // nwg % 8 == 0 (384 / 256)
    int swz = (blockIdx.x & 7) * per + (blockIdx.x >> 3);
    int m0 = (swz & 31) * 128;
    int n0 = (swz >> 5) * 128;
    int tid = threadIdx.x;
    int l = tid & 63, w = tid >> 6;
    int lr = l & 15, lg = l >> 4;
    int wr = (w >> 1) * 64, wc = (w & 1) * 64;
    int lrow = l >> 3;
    int lsw  = (((l & 7) ^ (lrow & 7)) << 3);      // swizzled source column (shorts)
    int rx   = lr & 7;                             // read-side row XOR key

    f32x4 z = {0.f, 0.f, 0.f, 0.f};
    f32x4 acc[4][4];
#pragma unroll
    for (int m = 0; m < 4; m++)
#pragma unroll
        for (int n = 0; n < 4; n++) acc[m][n] = z;

    for (int k0 = 0; k0 < K; k0 += 64) {
#pragma unroll
        for (int i = 0; i < 4; i++) {
            int ch = w * 4 + i;
            gload_lds16(A + (size_t)(m0 + ch * 8 + lrow) * K + k0 + lsw,
                        &As[ch * 8][0]);
        }
#pragma unroll
        for (int i = 0; i < 4; i++) {
            int ch = w * 4 + i;
            gload_lds16(Bt + (size_t)(n0 + ch * 8 + lrow) * K + k0 + lsw,
                        &Bs[ch * 8][0]);
        }
        __syncthreads();
#pragma unroll
        for (int kk = 0; kk < 2; kk++) {
            int jd = kk * 4 + lg;                  // 16B-granule index in row
            int gg = (jd ^ rx) << 3;               // swizzled read column
            short8 af[4], bf[4];
#pragma unroll
            for (int m = 0; m < 4; m++)
                af[m] = *(const short8*)&As[wr + m * 16 + lr][gg];
#pragma unroll
            for (int n = 0; n < 4; n++)
                bf[n] = *(const short8*)&Bs[wc + n * 16 + lr][gg];
#pragma unroll
            for (int m = 0; m < 4; m++)
#pragma unroll
                for (int n = 0; n < 4; n++)
                    acc[m][n] = __builtin_amdgcn_mfma_f32_16x16x32_bf16(
                        af[m], bf[n], acc[m][n], 0, 0, 0);
        }
        __syncthreads();
    }
#pragma unroll
    for (int m = 0; m < 4; m++)
#pragma unroll
        for (int r = 0; r < 4; r++) {
            int row = m0 + wr + m * 16 + lg * 4 + r;
            if (ROPE) {
                int h = (n0 + wc) >> 6;        // 64-col head block (wave-uniform)
                if (h < 20) {                  // Q heads 0..15, K heads 16..19
                    int t = row & (T_ - 1);
#pragma unroll
                    for (int n = 0; n < 2; n++) {
                        int d = n * 16 + lr;
                        float cd = cosT[t * 64 + d];
                        float sd = sinT[t * 64 + d];
                        float a = acc[m][n][r], bb = acc[m][n + 2][r];
                        acc[m][n][r]     = a * cd - bb * sd;
                        acc[m][n + 2][r] = bb * cd + a * sd;
                    }
                }
            }
#pragma unroll
            for (int n = 0; n < 4; n++) {
                int col = n0 + wc + n * 16 + lr;
                float v = acc[m][n][r];
                if (CF32) ((float*)Cv)[(size_t)row * N + col] = v;
                else      ((short*)Cv)[(size_t)row * N + col] = (short)bf16r(v);
            }
        }
}

// Flash attention v8 (R11-proven, 42.5us): gload_lds dbuf, 1 barrier/tile,
// swapped-operand 32x32x16, in-register P, m=0 softmax, cvt_pk, lac ones-MFMA,
// incremental staging pointers, split-K (nc=2 qt<32, nc=3 qt>=32).
__global__ __launch_bounds__(256, 4)
void k_attn(const short* __restrict__ qkv, const short* __restrict__ vt,
            short* __restrict__ opart, float* __restrict__ lpart) {
    __shared__ __align__(16) short KsL[2][4096];   // [buf][row*64 + swz-chunk*8]
    __shared__ __align__(16) short VsL[2][4096];   // [buf][d*64  + swz-chunk*8]
    int id = blockIdx.x;                 // 0..1279
    int bg = id & 7;
    int vv = 159 - (id >> 3);            // long chunks (high qt) first
    int qt, c, nc;
    if (vv < 64) { qt = vv >> 1; c = vv & 1; nc = 2; }
    else { int v2 = vv - 64; qt = 32 + (v2 & 31); c = v2 >> 5; nc = 3; }
    int slot = bg * 160 + vv;
    int b = bg & 1, g = (bg >> 1) & 3;
    int q0 = qt * 32;
    int nt = (qt + 2) >> 1;
    int t0 = c * nt / nc, t1 = (c + 1) * nt / nc;

    int tid = threadIdx.x;
    int w = tid >> 6;
    int l = tid & 63;
    int lc = l & 31, hi = l >> 5;
    const float s2 = 0.03187928f;        // log2(e)/sqrt(2048)
    size_t rowbase = (size_t)b * T_ * QKVN;
    int qcol = g * 256 + w * 64;
    int kcol = 1024 + g * 64;
    const short* vbase = vt + (size_t)((b * 4 + g) * 64) * T_;

    // Q as B-fragments, prescaled by s2
    short8 qf[4];
#pragma unroll
    for (int dkk = 0; dkk < 4; dkk++) {
        short8 raw = *(const short8*)(qkv + rowbase + (size_t)(q0 + lc) * QKVN
                                      + qcol + dkk * 16 + hi * 8);
        short8 sc;
#pragma unroll
        for (int x = 0; x < 8; x++) sc[x] = (short)bf16r(fbf16(raw[x]) * s2);
        qf[dkk] = sc;
    }

    const short one_bf = (short)0x3F80;  // bf16 1.0
    short8 ones8 = {one_bf, one_bf, one_bf, one_bf, one_bf, one_bf, one_bf, one_bf};

    // incremental staging pointers (advance by one 64-key tile per STAGE)
    int C0 = (w * 2) * 64 + l, C1 = (w * 2 + 1) * 64 + l;
    int r0 = C0 >> 3, j0 = (C0 & 7) ^ (r0 & 7);
    int r1 = C1 >> 3, j1 = (C1 & 7) ^ (r1 & 7);
    const short* kA0 = qkv + rowbase + (size_t)(t0 * 64 + r0) * QKVN + kcol + j0 * 8;
    const short* kA1 = qkv + rowbase + (size_t)(t0 * 64 + r1) * QKVN + kcol + j1 * 8;
    const short* vA0 = vbase + (size_t)r0 * T_ + t0 * 64 + j0 * 8;
    const short* vA1 = vbase + (size_t)r1 * T_ + t0 * 64 + j1 * 8;
    auto STAGE = [&](int bu) {
        gload_lds16(kA0, &KsL[bu][(w * 2) * 512]);
        gload_lds16(kA1, &KsL[bu][(w * 2 + 1) * 512]);
        gload_lds16(vA0, &VsL[bu][(w * 2) * 512]);
        gload_lds16(vA1, &VsL[bu][(w * 2 + 1) * 512]);
        kA0 += 64 * QKVN; kA1 += 64 * QKVN; vA0 += 64; vA1 += 64;
    };

    f32x16 Z16 = {0.f,0.f,0.f,0.f,0.f,0.f,0.f,0.f,0.f,0.f,0.f,0.f,0.f,0.f,0.f,0.f};
    f32x16 acc[2];
    acc[0] = Z16; acc[1] = Z16;
    f32x16 lac = Z16;                    // l accumulator (all rows identical)

    if (t0 < t1) STAGE(0);
    for (int kt = t0; kt < t1; kt++) {
        int bu = (kt - t0) & 1;
        int s0 = kt * 64;
        bool last = (kt == nt - 1);
        __syncthreads();     // implicit vmcnt-drain: buf[bu] loads complete;
                             // all waves done reading buf[bu^1] -> safe to refill
        if (kt + 1 < t1) STAGE(bu ^ 1);  // in flight across whole compute

#pragma unroll
        for (int kf = 0; kf < 2; kf++) {
            f32x16 s = Z16;
            __builtin_amdgcn_s_setprio(1);
#pragma unroll
            for (int dkk = 0; dkk < 4; dkk++) {
                int r = kf * 32 + lc;
                int jd = dkk * 2 + hi;
                short8 ka = *(const short8*)&KsL[bu][r * 64 + ((jd ^ (r & 7)) << 3)];
                s = __builtin_amdgcn_mfma_f32_32x32x16_bf16(ka, qf[dkk], s, 0, 0, 0);
            }
            __builtin_amdgcn_s_setprio(0);
            float p[16];
            if (last) {
                int qrow = q0 + lc;
                int kb = s0 + kf * 32 + hi * 4;
#pragma unroll
                for (int reg = 0; reg < 16; reg++) {
                    int key = kb + (reg & 3) + ((reg >> 2) << 3);
                    p[reg] = (key <= qrow) ? exp2f(s[reg]) : 0.f;
                }
            } else {
#pragma unroll
                for (int reg = 0; reg < 16; reg++) p[reg] = exp2f(s[reg]);
            }
            unsigned pk[4][2];
#pragma unroll
            for (int sb = 0; sb < 4; sb++) {
                pk[sb][0] = cvtpk(p[4 * sb],     p[4 * sb + 1]);
                pk[sb][1] = cvtpk(p[4 * sb + 2], p[4 * sb + 3]);
            }
            __builtin_amdgcn_s_setprio(1);
#pragma unroll
            for (int kk = 0; kk < 2; kk++) {
                unsigned a0 = pk[2 * kk][0], b0 = pk[2 * kk + 1][0];
                unsigned a1 = pk[2 * kk][1], b1 = pk[2 * kk + 1][1];
                plswap(a0, b0);
                plswap(a1, b1);
                union { unsigned u[4]; short8 s8; } pb;
                pb.u[0] = a0; pb.u[1] = a1; pb.u[2] = b0; pb.u[3] = b1;
#pragma unroll
                for (int df = 0; df < 2; df++) {
                    int r = df * 32 + lc;
                    int jk = kf * 4 + kk * 2 + hi;
                    short8 va = *(const short8*)&VsL[bu][r * 64 + ((jk ^ (r & 7)) << 3)];
                    acc[df] = __builtin_amdgcn_mfma_f32_32x32x16_bf16(va, pb.s8, acc[df], 0, 0, 0);
                }
                lac = __builtin_amdgcn_mfma_f32_32x32x16_bf16(ones8, pb.s8, lac, 0, 0, 0);
            }
            __builtin_amdgcn_s_setprio(0);
        }
    }

    float lt = lac[0];                   // full sum over keys (both hi halves)

    // bf16 partials: [slot][32 rows][256 cols]
    short* ob = opart + (size_t)slot * 8192 + lc * 256 + w * 64;
#pragma unroll
    for (int df = 0; df < 2; df++)
#pragma unroll
        for (int sb = 0; sb < 4; sb++) {
            unsigned u0 = cvtpk(acc[df][4 * sb],     acc[df][4 * sb + 1]);
            unsigned u1 = cvtpk(acc[df][4 * sb + 2], acc[df][4 * sb + 3]);
            uint2 uv = {u0, u1};
            *(uint2*)(ob + df * 32 + sb * 8 + hi * 4) = uv;
        }
    if (hi == 0) lpart[slot * 128 + lc * 4 + w] = lt;
}

// combine all chunks: out = sum(O_c) / sum(l_c)
__global__ __launch_bounds__(256)
void k_comb(const short* __restrict__ opart, const float* __restrict__ lpart,
            short* __restrict__ attn) {
    int id = blockIdx.x;             // 0..511
    int bg = id & 7, qt = id >> 3;
    int b = bg & 1, g = (bg >> 1) & 3;
    int t = threadIdx.x;
    int row = t >> 3, s = t & 7;
    int head = s >> 1, colseg = s * 32;
    int nc = (qt < 32) ? 2 : 3;
    float acc[32];
#pragma unroll
    for (int i = 0; i < 32; i++) acc[i] = 0.f;
    float lsum = 0.f;
    for (int c = 0; c < nc; c++) {
        int vv = (qt < 32) ? (2 * qt + c) : (64 + (qt - 32) + 32 * c);
        int oid = bg * 160 + vv;
        lsum += lpart[oid * 128 + row * 4 + head];
        const short* ob = opart + (size_t)oid * 8192 + row * 256 + colseg;
#pragma unroll
        for (int i = 0; i < 4; i++) {
            uint4 v = *(const uint4*)(ob + i * 8);
            const short* vs = (const short*)&v;
#pragma unroll
            for (int j = 0; j < 8; j++) acc[i * 8 + j] += fbf16(vs[j]);
        }
    }
    float inv = 1.0f / lsum;
    unsigned out[16];
#pragma unroll
    for (int i = 0; i < 16; i++)
        out[i] = cvtpk(acc[2 * i] * inv, acc[2 * i + 1] * inv);
    short* dst = attn + ((size_t)(b * T_ + qt * 32 + row)) * DOUT_ + g * 256 + colseg;
#pragma unroll
    for (int i = 0; i < 4; i++) *(uint4*)(dst + i * 8) = *(const uint4*)&out[i * 4];
}

extern "C" void kernel_launch(void* const* d_in, const int* in_sizes, int n_in,
                              void* d_out, int out_size, void* d_ws, size_t ws_size,
                              hipStream_t stream) {
    const float* x    = (const float*)d_in[0];
    const float* Wq   = (const float*)d_in[1];
    const float* Wk   = (const float*)d_in[2];
    const float* Wv   = (const float*)d_in[3];
    const float* Wo   = (const float*)d_in[4];
    const float* cosT = (const float*)d_in[5];
    const float* sinT = (const float*)d_in[6];

    char* ws = (char*)d_ws;
    short* WT    = (short*)(ws);             // [1536][1024] bf16
    short* WoT   = (short*)(ws + 3145728);   // [1024][1024] bf16
    short* QKV   = (short*)(ws + 5242880);   // [4096][1536] bf16
    short* ATT   = (short*)(ws + 17825792);  // [4096][1024] bf16
    short* VT    = (short*)(ws + 26214400);  // [8][64][2048] bf16
    short* XB    = (short*)(ws + 28311552);  // [4096][1024] bf16 (phase-1 only)
    short* OPART = (short*)(ws + 28311552);  // [1280][32][256] bf16 (aliases XB)
    float* LPART = (float*)(ws + 49283072);  // [1280][128] f32  (end 49938432)

    k_prep<<<1664, 256, 0, stream>>>(x, Wq, Wk, Wv, Wo, XB, WT, WoT);
    k_gemm<0, 1><<<384, 256, 0, stream>>>(XB, WT, (void*)QKV,
                                          4096, 1536, 1024, cosT, sinT);
    k_vt<<<256, 256, 0, stream>>>(QKV, VT);
    k_attn<<<1280, 256, 0, stream>>>(QKV, VT, OPART, LPART);
    k_comb<<<512, 256, 0, stream>>>(OPART, LPART, ATT);
    k_gemm<1, 0><<<256, 256, 0, stream>>>(ATT, WoT, d_out,
                                          4096, 1024, 1024, nullptr, nullptr);
}

// Round 15
// 94.132 us; speedup vs baseline: 1.1586x; 1.1586x over previous
//
#include <hip/hip_runtime.h>
#include <hip/hip_bf16.h>

typedef __attribute__((ext_vector_type(8))) short short8;
typedef __attribute__((ext_vector_type(4))) float f32x4;
typedef __attribute__((ext_vector_type(16))) float f32x16;

#define T_    2048
#define QKVN  1536
#define DOUT_ 1024

__device__ __forceinline__ unsigned short bf16r(float f) {
    union { float f; unsigned u; } v; v.f = f;
    unsigned r = v.u + 0x7fffu + ((v.u >> 16) & 1u);   // round-to-nearest-even
    return (unsigned short)(r >> 16);
}
__device__ __forceinline__ float fbf16(short s) {
    union { unsigned u; float f; } v; v.u = ((unsigned)(unsigned short)s) << 16;
    return v.f;
}
__device__ __forceinline__ void plswap(unsigned &a, unsigned &b) {
    asm volatile("v_permlane32_swap_b32 %0, %1" : "+v"(a), "+v"(b));
}
// packed f32x2 -> bf16x2 (RNE), one HW instruction
__device__ __forceinline__ unsigned cvtpk(float lo, float hi) {
    unsigned r;
    asm("v_cvt_pk_bf16_f32 %0, %1, %2" : "=v"(r) : "v"(lo), "v"(hi));
    return r;
}
// async global->LDS, 16B per lane; LDS dest = wave-uniform base + lane*16
__device__ __forceinline__ void gload_lds16(const void* g, void* l) {
    __builtin_amdgcn_global_load_lds(
        (const __attribute__((address_space(1))) void*)g,
        (__attribute__((address_space(3))) void*)l, 16, 0, 0);
}

// Fused pre-pass: blocks 0-255 Wq^T, 256-319 Wk^T, 320-383 Wv^T, 384-639 Wo^T,
// 640-1663 x->bf16 (2 grid-stride reps).
__global__ __launch_bounds__(256)
void k_prep(const float* __restrict__ x, const float* __restrict__ Wq,
            const float* __restrict__ Wk, const float* __restrict__ Wv,
            const float* __restrict__ Wo, short* __restrict__ XB,
            short* __restrict__ WT, short* __restrict__ WoT) {
    __shared__ short tile[64][72];
    int blk = blockIdx.x;
    int t = threadIdx.x;
    if (blk >= 640) {                        // x f32 -> bf16, 8 elems/thread
        int i = (blk - 640) * 256 + t;
#pragma unroll
        for (int rep = 0; rep < 2; rep++, i += 262144) {
            const float* s = x + (size_t)i * 8;
            float4 f1 = *(const float4*)s;
            float4 f2 = *(const float4*)(s + 4);
            uint4 o;
            o.x = (unsigned)bf16r(f1.x) | ((unsigned)bf16r(f1.y) << 16);
            o.y = (unsigned)bf16r(f1.z) | ((unsigned)bf16r(f1.w) << 16);
            o.z = (unsigned)bf16r(f2.x) | ((unsigned)bf16r(f2.y) << 16);
            o.w = (unsigned)bf16r(f2.z) | ((unsigned)bf16r(f2.w) << 16);
            *(uint4*)(XB + (size_t)i * 8) = o;
        }
        return;
    }
    const float* src; short* dst; int N, bx, by;
    if (blk < 256)      { src = Wq; dst = WT;              N = 1024; bx = blk & 15;         by = blk >> 4; }
    else if (blk < 320) { src = Wk; dst = WT + 1024*1024;  N = 256;  bx = (blk-256) & 15;   by = (blk-256) >> 4; }
    else if (blk < 384) { src = Wv; dst = WT + 1280*1024;  N = 256;  bx = (blk-320) & 15;   by = (blk-320) >> 4; }
    else                { src = Wo; dst = WoT;             N = 1024; bx = (blk-384) & 15;   by = (blk-384) >> 4; }
    const int K = 1024;
    int tk = bx * 64, tn = by * 64;
    int r4 = t >> 6, c = t & 63;
#pragma unroll
    for (int i = 0; i < 16; i++) {
        int row = i * 4 + r4;
        tile[c][row] = (short)bf16r(src[(size_t)(tk + row) * N + tn + c]);
    }
    __syncthreads();
    int row = t >> 2, seg = t & 3;
    short8 a = *(const short8*)&tile[row][seg * 16];
    short8 b = *(const short8*)&tile[row][seg * 16 + 8];
    *(short8*)&dst[(size_t)(tn + row) * K + tk + seg * 16]     = a;
    *(short8*)&dst[(size_t)(tn + row) * K + tk + seg * 16 + 8] = b;
}

// C[M][N] = A[M][K] * Bt[N][K]^T, bf16. Tile 64x128, BK=64 (R11-proven),
// gload_lds staging, both-sides XOR swizzle. VTW=1: for V-column blocks
// (n0>=1280) also emit VT[(b*4+g)*64+d][t] via LDS transpose (k_vt fused).
template <int CF32, int ROPE, int VTW>
__global__ __launch_bounds__(256, 4)
void k_gemm(const short* __restrict__ A, const short* __restrict__ Bt,
            void* __restrict__ Cv, int M, int N, int K,
            const float* __restrict__ cosT, const float* __restrict__ sinT,
            short* __restrict__ vtp) {
    __shared__ __align__(16) short lds[12288];     // 24 KB
    short (*As)[64] = (short(*)[64])lds;           // [64][64]
    short (*Bs)[64] = (short(*)[64])(lds + 4096);  // [128][64]
    int tid = threadIdx.x;
    int l = tid & 63, w = tid >> 6;
    int lr = l & 15, lg = l >> 4;
    int m0 = blockIdx.x * 64;
    int n0 = blockIdx.y * 128;
    int wr = (w >> 1) * 32, wc = (w & 1) * 64;
    int lrow = l >> 3;
    int lsw  = (((l & 7) ^ (lrow & 7)) << 3);      // swizzled source column (shorts)
    int rx   = lr & 7;                             // read-side row XOR key

    f32x4 z = {0.f, 0.f, 0.f, 0.f};
    f32x4 acc[2][4];
#pragma unroll
    for (int m = 0; m < 2; m++)
#pragma unroll
        for (int n = 0; n < 4; n++) acc[m][n] = z;

    for (int k0 = 0; k0 < K; k0 += 64) {
#pragma unroll
        for (int i = 0; i < 2; i++) {
            int ch = w * 2 + i;
            gload_lds16(A + (size_t)(m0 + ch * 8 + lrow) * K + k0 + lsw,
                        &As[ch * 8][0]);
        }
#pragma unroll
        for (int i = 0; i < 4; i++) {
            int ch = w * 4 + i;
            gload_lds16(Bt + (size_t)(n0 + ch * 8 + lrow) * K + k0 + lsw,
                        &Bs[ch * 8][0]);
        }
        __syncthreads();
#pragma unroll
        for (int kk = 0; kk < 2; kk++) {
            int jd = kk * 4 + lg;                  // 16B-granule index in row
            int gg = (jd ^ rx) << 3;               // swizzled read column
            short8 af[2], bf[4];
#pragma unroll
            for (int m = 0; m < 2; m++)
                af[m] = *(const short8*)&As[wr + m * 16 + lr][gg];
#pragma unroll
            for (int n = 0; n < 4; n++)
                bf[n] = *(const short8*)&Bs[wc + n * 16 + lr][gg];
#pragma unroll
            for (int m = 0; m < 2; m++)
#pragma unroll
                for (int n = 0; n < 4; n++)
                    acc[m][n] = __builtin_amdgcn_mfma_f32_16x16x32_bf16(
                        af[m], bf[n], acc[m][n], 0, 0, 0);
        }
        __syncthreads();
    }
#pragma unroll
    for (int m = 0; m < 2; m++)
#pragma unroll
        for (int r = 0; r < 4; r++) {
            int row = m0 + wr + m * 16 + lg * 4 + r;
            if (ROPE) {
                int h = (n0 + wc) >> 6;        // 64-col head block (wave-uniform)
                if (h < 20) {                  // Q heads 0..15, K heads 16..19
                    int t = row & (T_ - 1);
#pragma unroll
                    for (int n = 0; n < 2; n++) {
                        int d = n * 16 + lr;
                        float cd = cosT[t * 64 + d];
                        float sd = sinT[t * 64 + d];
                        float a = acc[m][n][r], bb = acc[m][n + 2][r];
                        acc[m][n][r]     = a * cd - bb * sd;
                        acc[m][n + 2][r] = bb * cd + a * sd;
                    }
                }
            }
#pragma unroll
            for (int n = 0; n < 4; n++) {
                int col = n0 + wc + n * 16 + lr;
                float v = acc[m][n][r];
                if (CF32) ((float*)Cv)[(size_t)row * N + col] = v;
                else      ((short*)Cv)[(size_t)row * N + col] = (short)bf16r(v);
            }
        }
    if (VTW && n0 >= 1280) {
        // fused k_vt: transpose this 64x128 V-tile through LDS (pad 72: 2-way
        // alias only) and write VT coalesced. LDS is dead after loop barrier.
        short (*vt_)[72] = (short(*)[72])lds;      // [128 cols][72]
#pragma unroll
        for (int m = 0; m < 2; m++)
#pragma unroll
            for (int r = 0; r < 4; r++)
#pragma unroll
                for (int n = 0; n < 4; n++)
                    vt_[wc + n * 16 + lr][wr + m * 16 + lg * 4 + r] =
                        (short)bf16r(acc[m][n][r]);
        __syncthreads();
        int b = m0 >> 11;                          // row block entirely in one b
        int t0sp = m0 & (T_ - 1);
        int g2 = (n0 - 1280) >> 6;                 // first g of this tile
#pragma unroll
        for (int i = 0; i < 4; i++) {
            int q = i * 256 + tid;                 // 1024 uint4 chunks
            int col = q >> 3, seg = q & 7;
            short* dst = vtp + ((size_t)((b * 4 + g2 + (col >> 6)) * 64 + (col & 63))) * T_
                         + t0sp + seg * 8;
            *(uint4*)dst = *(const uint4*)&vt_[col][seg * 8];
        }
    }
}

// Flash attention v8 (R11-proven, 42.5us): gload_lds dbuf, 1 barrier/tile,
// swapped-operand 32x32x16, in-register P, m=0 softmax, cvt_pk, lac ones-MFMA,
// incremental staging pointers, split-K (nc=2 qt<32, nc=3 qt>=32).
__global__ __launch_bounds__(256, 4)
void k_attn(const short* __restrict__ qkv, const short* __restrict__ vt,
            short* __restrict__ opart, float* __restrict__ lpart) {
    __shared__ __align__(16) short KsL[2][4096];   // [buf][row*64 + swz-chunk*8]
    __shared__ __align__(16) short VsL[2][4096];   // [buf][d*64  + swz-chunk*8]
    int id = blockIdx.x;                 // 0..1279
    int bg = id & 7;
    int vv = 159 - (id >> 3);            // long chunks (high qt) first
    int qt, c, nc;
    if (vv < 64) { qt = vv >> 1; c = vv & 1; nc = 2; }
    else { int v2 = vv - 64; qt = 32 + (v2 & 31); c = v2 >> 5; nc = 3; }
    int slot = bg * 160 + vv;
    int b = bg & 1, g = (bg >> 1) & 3;
    int q0 = qt * 32;
    int nt = (qt + 2) >> 1;
    int t0 = c * nt / nc, t1 = (c + 1) * nt / nc;

    int tid = threadIdx.x;
    int w = tid >> 6;
    int l = tid & 63;
    int lc = l & 31, hi = l >> 5;
    const float s2 = 0.03187928f;        // log2(e)/sqrt(2048)
    size_t rowbase = (size_t)b * T_ * QKVN;
    int qcol = g * 256 + w * 64;
    int kcol = 1024 + g * 64;
    const short* vbase = vt + (size_t)((b * 4 + g) * 64) * T_;

    // Q as B-fragments, prescaled by s2
    short8 qf[4];
#pragma unroll
    for (int dkk = 0; dkk < 4; dkk++) {
        short8 raw = *(const short8*)(qkv + rowbase + (size_t)(q0 + lc) * QKVN
                                      + qcol + dkk * 16 + hi * 8);
        short8 sc;
#pragma unroll
        for (int x = 0; x < 8; x++) sc[x] = (short)bf16r(fbf16(raw[x]) * s2);
        qf[dkk] = sc;
    }

    const short one_bf = (short)0x3F80;  // bf16 1.0
    short8 ones8 = {one_bf, one_bf, one_bf, one_bf, one_bf, one_bf, one_bf, one_bf};

    // incremental staging pointers (advance by one 64-key tile per STAGE)
    int C0 = (w * 2) * 64 + l, C1 = (w * 2 + 1) * 64 + l;
    int r0 = C0 >> 3, j0 = (C0 & 7) ^ (r0 & 7);
    int r1 = C1 >> 3, j1 = (C1 & 7) ^ (r1 & 7);
    const short* kA0 = qkv + rowbase + (size_t)(t0 * 64 + r0) * QKVN + kcol + j0 * 8;
    const short* kA1 = qkv + rowbase + (size_t)(t0 * 64 + r1) * QKVN + kcol + j1 * 8;
    const short* vA0 = vbase + (size_t)r0 * T_ + t0 * 64 + j0 * 8;
    const short* vA1 = vbase + (size_t)r1 * T_ + t0 * 64 + j1 * 8;
    auto STAGE = [&](int bu) {
        gload_lds16(kA0, &KsL[bu][(w * 2) * 512]);
        gload_lds16(kA1, &KsL[bu][(w * 2 + 1) * 512]);
        gload_lds16(vA0, &VsL[bu][(w * 2) * 512]);
        gload_lds16(vA1, &VsL[bu][(w * 2 + 1) * 512]);
        kA0 += 64 * QKVN; kA1 += 64 * QKVN; vA0 += 64; vA1 += 64;
    };

    f32x16 Z16 = {0.f,0.f,0.f,0.f,0.f,0.f,0.f,0.f,0.f,0.f,0.f,0.f,0.f,0.f,0.f,0.f};
    f32x16 acc[2];
    acc[0] = Z16; acc[1] = Z16;
    f32x16 lac = Z16;                    // l accumulator (all rows identical)

    if (t0 < t1) STAGE(0);
    for (int kt = t0; kt < t1; kt++) {
        int bu = (kt - t0) & 1;
        int s0 = kt * 64;
        bool last = (kt == nt - 1);
        __syncthreads();     // implicit vmcnt-drain: buf[bu] loads complete;
                             // all waves done reading buf[bu^1] -> safe to refill
        if (kt + 1 < t1) STAGE(bu ^ 1);  // in flight across whole compute

#pragma unroll
        for (int kf = 0; kf < 2; kf++) {
            f32x16 s = Z16;
            __builtin_amdgcn_s_setprio(1);
#pragma unroll
            for (int dkk = 0; dkk < 4; dkk++) {
                int r = kf * 32 + lc;
                int jd = dkk * 2 + hi;
                short8 ka = *(const short8*)&KsL[bu][r * 64 + ((jd ^ (r & 7)) << 3)];
                s = __builtin_amdgcn_mfma_f32_32x32x16_bf16(ka, qf[dkk], s, 0, 0, 0);
            }
            __builtin_amdgcn_s_setprio(0);
            float p[16];
            if (last) {
                int qrow = q0 + lc;
                int kb = s0 + kf * 32 + hi * 4;
#pragma unroll
                for (int reg = 0; reg < 16; reg++) {
                    int key = kb + (reg & 3) + ((reg >> 2) << 3);
                    p[reg] = (key <= qrow) ? exp2f(s[reg]) : 0.f;
                }
            } else {
#pragma unroll
                for (int reg = 0; reg < 16; reg++) p[reg] = exp2f(s[reg]);
            }
            unsigned pk[4][2];
#pragma unroll
            for (int sb = 0; sb < 4; sb++) {
                pk[sb][0] = cvtpk(p[4 * sb],     p[4 * sb + 1]);
                pk[sb][1] = cvtpk(p[4 * sb + 2], p[4 * sb + 3]);
            }
            __builtin_amdgcn_s_setprio(1);
#pragma unroll
            for (int kk = 0; kk < 2; kk++) {
                unsigned a0 = pk[2 * kk][0], b0 = pk[2 * kk + 1][0];
                unsigned a1 = pk[2 * kk][1], b1 = pk[2 * kk + 1][1];
                plswap(a0, b0);
                plswap(a1, b1);
                union { unsigned u[4]; short8 s8; } pb;
                pb.u[0] = a0; pb.u[1] = a1; pb.u[2] = b0; pb.u[3] = b1;
#pragma unroll
                for (int df = 0; df < 2; df++) {
                    int r = df * 32 + lc;
                    int jk = kf * 4 + kk * 2 + hi;
                    short8 va = *(const short8*)&VsL[bu][r * 64 + ((jk ^ (r & 7)) << 3)];
                    acc[df] = __builtin_amdgcn_mfma_f32_32x32x16_bf16(va, pb.s8, acc[df], 0, 0, 0);
                }
                lac = __builtin_amdgcn_mfma_f32_32x32x16_bf16(ones8, pb.s8, lac, 0, 0, 0);
            }
            __builtin_amdgcn_s_setprio(0);
        }
    }

    float lt = lac[0];                   // full sum over keys (both hi halves)

    // bf16 partials: [slot][32 rows][256 cols]
    short* ob = opart + (size_t)slot * 8192 + lc * 256 + w * 64;
#pragma unroll
    for (int df = 0; df < 2; df++)
#pragma unroll
        for (int sb = 0; sb < 4; sb++) {
            unsigned u0 = cvtpk(acc[df][4 * sb],     acc[df][4 * sb + 1]);
            unsigned u1 = cvtpk(acc[df][4 * sb + 2], acc[df][4 * sb + 3]);
            uint2 uv = {u0, u1};
            *(uint2*)(ob + df * 32 + sb * 8 + hi * 4) = uv;
        }
    if (hi == 0) lpart[slot * 128 + lc * 4 + w] = lt;
}

// combine all chunks: out = sum(O_c) / sum(l_c)
__global__ __launch_bounds__(256)
void k_comb(const short* __restrict__ opart, const float* __restrict__ lpart,
            short* __restrict__ attn) {
    int id = blockIdx.x;             // 0..511
    int bg = id & 7, qt = id >> 3;
    int b = bg & 1, g = (bg >> 1) & 3;
    int t = threadIdx.x;
    int row = t >> 3, s = t & 7;
    int head = s >> 1, colseg = s * 32;
    int nc = (qt < 32) ? 2 : 3;
    float acc[32];
#pragma unroll
    for (int i = 0; i < 32; i++) acc[i] = 0.f;
    float lsum = 0.f;
    for (int c = 0; c < nc; c++) {
        int vv = (qt < 32) ? (2 * qt + c) : (64 + (qt - 32) + 32 * c);
        int oid = bg * 160 + vv;
        lsum += lpart[oid * 128 + row * 4 + head];
        const short* ob = opart + (size_t)oid * 8192 + row * 256 + colseg;
#pragma unroll
        for (int i = 0; i < 4; i++) {
            uint4 v = *(const uint4*)(ob + i * 8);
            const short* vs = (const short*)&v;
#pragma unroll
            for (int j = 0; j < 8; j++) acc[i * 8 + j] += fbf16(vs[j]);
        }
    }
    float inv = 1.0f / lsum;
    unsigned out[16];
#pragma unroll
    for (int i = 0; i < 16; i++)
        out[i] = cvtpk(acc[2 * i] * inv, acc[2 * i + 1] * inv);
    short* dst = attn + ((size_t)(b * T_ + qt * 32 + row)) * DOUT_ + g * 256 + colseg;
#pragma unroll
    for (int i = 0; i < 4; i++) *(uint4*)(dst + i * 8) = *(const uint4*)&out[i * 4];
}

extern "C" void kernel_launch(void* const* d_in, const int* in_sizes, int n_in,
                              void* d_out, int out_size, void* d_ws, size_t ws_size,
                              hipStream_t stream) {
    const float* x    = (const float*)d_in[0];
    const float* Wq   = (const float*)d_in[1];
    const float* Wk   = (const float*)d_in[2];
    const float* Wv   = (const float*)d_in[3];
    const float* Wo   = (const float*)d_in[4];
    const float* cosT = (const float*)d_in[5];
    const float* sinT = (const float*)d_in[6];

    char* ws = (char*)d_ws;
    short* WT    = (short*)(ws);             // [1536][1024] bf16
    short* WoT   = (short*)(ws + 3145728);   // [1024][1024] bf16
    short* QKV   = (short*)(ws + 5242880);   // [4096][1536] bf16
    short* ATT   = (short*)(ws + 17825792);  // [4096][1024] bf16
    short* VT    = (short*)(ws + 26214400);  // [8][64][2048] bf16
    short* XB    = (short*)(ws + 28311552);  // [4096][1024] bf16 (phase-1 only)
    short* OPART = (short*)(ws + 28311552);  // [1280][32][256] bf16 (aliases XB)
    float* LPART = (float*)(ws + 49283072);  // [1280][128] f32  (end 49938432)

    k_prep<<<1664, 256, 0, stream>>>(x, Wq, Wk, Wv, Wo, XB, WT, WoT);
    k_gemm<0, 1, 1><<<dim3(64, 12), 256, 0, stream>>>(XB, WT, (void*)QKV,
                                                      4096, 1536, 1024, cosT, sinT, VT);
    k_attn<<<1280, 256, 0, stream>>>(QKV, VT, OPART, LPART);
    k_comb<<<512, 256, 0, stream>>>(OPART, LPART, ATT);
    k_gemm<1, 0, 0><<<dim3(64, 8), 256, 0, stream>>>(ATT, WoT, d_out,
                                                     4096, 1024, 1024, nullptr, nullptr, nullptr);
}